// Round 1
// baseline (418.558 us; speedup 1.0000x reference)
//
#include <hip/hip_runtime.h>
#include <math.h>

typedef __attribute__((ext_vector_type(8))) short short8;
typedef __attribute__((ext_vector_type(4))) float f32x4;
typedef unsigned short u16;
typedef unsigned int u32;

#define HW   96
#define LPIX 9216
static constexpr float kScale = 0.17677669529663687f;  // 1/sqrt(32)

__device__ inline u16 f2bf(float f) {
    u32 x = __float_as_uint(f);
    return (u16)((x + 0x7fffu + ((x >> 16) & 1u)) >> 16);   // RNE
}
__device__ inline float bf2f(u16 v) { return __uint_as_float((u32)v << 16); }

// ---------------------------------------------------------------------------
// NCHW fp32 -> NHWC bf16 transpose-cast. grid (96 y, 8 b), block 256.
// ---------------------------------------------------------------------------
template <int C>
__global__ __launch_bounds__(256) void cast_nchw_nhwc(
    const float* __restrict__ in, u16* __restrict__ out)
{
    const int y = blockIdx.x, b = blockIdx.y, tid = threadIdx.x;
    __shared__ float sT[HW * C];
    for (int i = tid; i < HW * C; i += 256) {
        int c = i / HW, xx = i - c * HW;
        sT[xx * C + c] = in[(((size_t)b * C + c) * HW + y) * HW + xx];
    }
    __syncthreads();
    for (int i = tid; i < HW * (C / 8); i += 256) {
        int c8 = i % (C / 8), xx = i / (C / 8);
        union { short8 v8; u16 u[8]; } pk;
#pragma unroll
        for (int j = 0; j < 8; ++j) pk.u[j] = f2bf(sT[xx * C + c8 * 8 + j]);
        *(short8*)&out[(((size_t)b * HW + y) * HW + xx) * C + c8 * 8] = pk.v8;
    }
}

// ---------------------------------------------------------------------------
// conv weights [co 128][ci CIN][3][3] fp32 -> [f 9][ci/32][co 128][32] bf16
// ---------------------------------------------------------------------------
__global__ void cast_conv_w(const float* __restrict__ w, u16* __restrict__ wp, int CIN)
{
    int n = 9 * CIN * 128;
    int i = blockIdx.x * 256 + threadIdx.x;
    if (i >= n) return;
    int cil = i & 31; int t = i >> 5; int co = t & 127; int t2 = t >> 7;
    int nc5 = CIN >> 5;
    int c5 = t2 % nc5; int f = t2 / nc5;
    int ci = c5 * 32 + cil;
    wp[i] = f2bf(w[(size_t)(co * CIN + ci) * 9 + f]);
}

// dense matrix fp32 -> bf16 (same layout)
__global__ void cast_mat(const float* __restrict__ in, u16* __restrict__ out, int n)
{
    int i = blockIdx.x * 256 + threadIdx.x;
    if (i < n) out[i] = f2bf(in[i]);
}

// ---------------------------------------------------------------------------
// conv3x3 + BN + ReLU, halo-tile implicit GEMM, v2 (latency-oriented):
//  * 96-px row-aligned blocks -> grid (96,8)=768 = exactly 3 blocks/CU (even),
//    LDS 46.4 KB -> 3 blocks/CU resident, 12 waves/CU cap (was 2.25 blocks).
//  * 32-ci chunks, DOUBLE-BUFFERED halo (2 x 290x40 u16 = 46.4 KB) with
//    T14 async-stage split: global loads for chunk c+2 are issued right
//    after the ds_write of chunk c+1 and stay in flight across one full
//    compute phase. Chunk barrier is lgkmcnt(0)+s_barrier ONLY (no vmcnt
//    drain), so the staged loads survive the barrier.
//  * wave tile M=64(co) x N=48(px): acc[4][3]=48 VGPR (was 64) -> headroom
//    for the compiler to hoist per-tap global weight loads.
//  * 108 MFMAs per wave between barriers, 1 barrier per chunk.
// block 256 (2x2 waves: wm=co half, wn=px half of 48).
// ---------------------------------------------------------------------------
template <int CIN, bool OUT_F32>
__global__ __launch_bounds__(256, 3) void conv_gemm(
    const u16* __restrict__ in, const u16* __restrict__ wp,
    const float* __restrict__ g, const float* __restrict__ be, void* outv)
{
    constexpr int NC     = CIN / 32;     // 32-ci chunks (2 or 4)
    constexpr int HROWS  = 290;          // flat halo pixels: l0-97 .. l0+192
    constexpr int HPITCH = 40;           // u16 pitch per halo row (80 B, 2-way free)
    constexpr int NGRAN  = HROWS * 4;    // 16B granules per chunk = 1160

    const int l0 = blockIdx.x * 96;      // one full image row per block
    const int b  = blockIdx.y;
    const int tid = threadIdx.x, lane = tid & 63, wv = tid >> 6;
    const int wm = wv >> 1, wn = wv & 1;
    const int lx = lane & 15, q = lane >> 4;

    __shared__ __align__(16) char smem[2 * HROWS * HPITCH * 2];   // 46,400 B
    float* sT = (float*)smem;            // epilogue [96][65] f32 (24,960 B)

    // per-lane pixel coords for the 3 B-fragment pixel groups
    int py_[3], px_[3];
#pragma unroll
    for (int nt = 0; nt < 3; ++nt) {
        int l = l0 + wn * 48 + nt * 16 + lx;
        py_[nt] = l / 96; px_[nt] = l - py_[nt] * 96;
    }

    f32x4 acc[4][3];
#pragma unroll
    for (int mt = 0; mt < 4; ++mt)
#pragma unroll
        for (int nt = 0; nt < 3; ++nt) acc[mt][nt] = (f32x4){0.f, 0.f, 0.f, 0.f};

    const u16* inb = in + (size_t)b * LPIX * CIN;
    short8 st[5];                        // staged granules (20 VGPR)

    auto LOADC = [&](int c) {            // issue global loads for chunk c
#pragma unroll
        for (int i = 0; i < 5; ++i) {
            int gi = tid + i * 256;
            short8 v = (short8){0, 0, 0, 0, 0, 0, 0, 0};
            if (gi < NGRAN) {
                int hp = gi >> 2, k = gi & 3;
                int lh = l0 - 97 + hp;
                if ((unsigned)lh < (unsigned)LPIX)
                    v = *(const short8*)&inb[(size_t)lh * CIN + c * 32 + k * 8];
            }
            st[i] = v;
        }
    };
    auto WRITEC = [&](int bsel) {        // ds_write staged regs -> halo buffer
        u16* sB = (u16*)smem + bsel * (HROWS * HPITCH);
#pragma unroll
        for (int i = 0; i < 5; ++i) {
            int gi = tid + i * 256;
            if (gi < NGRAN)
                *(short8*)&sB[(gi >> 2) * HPITCH + (gi & 3) * 8] = st[i];
        }
    };
    auto COMPUTE = [&](int c, int bsel) {
        const u16* sB = (const u16*)smem + bsel * (HROWS * HPITCH);
#pragma unroll
        for (int f = 0; f < 9; ++f) {
            const int dy = f / 3 - 1, dx = f % 3 - 1;
            const int off = dy * 96 + dx + 97;       // in [0,194]
            bool ok[3];
#pragma unroll
            for (int nt = 0; nt < 3; ++nt) {
                int yy = py_[nt] + dy, xx = px_[nt] + dx;
                ok[nt] = ((unsigned)yy < 96u) & ((unsigned)xx < 96u);
            }
            short8 af[4], bfr[3];
            // weights direct from global: 1024B/wave coalesced, L2-hot
#pragma unroll
            for (int mt = 0; mt < 4; ++mt)
                af[mt] = *(const short8*)&wp[(size_t)(((f * NC + c) * 128
                                                       + wm * 64 + mt * 16 + lx) * 32 + q * 8)];
#pragma unroll
            for (int nt = 0; nt < 3; ++nt) {
                short8 t8 = *(const short8*)&sB[(wn * 48 + nt * 16 + lx + off) * HPITCH + q * 8];
                bfr[nt] = ok[nt] ? t8 : (short8){0, 0, 0, 0, 0, 0, 0, 0};
            }
#pragma unroll
            for (int mt = 0; mt < 4; ++mt)
#pragma unroll
                for (int nt = 0; nt < 3; ++nt)
                    acc[mt][nt] = __builtin_amdgcn_mfma_f32_16x16x32_bf16(
                        af[mt], bfr[nt], acc[mt][nt], 0, 0, 0);
        }
    };

    // barrier that does NOT drain vmcnt: staged global loads stay in flight
#define CHUNK_BAR() do {                                             \
        asm volatile("s_waitcnt lgkmcnt(0)" ::: "memory");           \
        __builtin_amdgcn_s_barrier();                                \
        asm volatile("" ::: "memory");                               \
    } while (0)

    // prologue: stage chunk 0, issue chunk 1
    LOADC(0);
    WRITEC(0);
    LOADC(1);
    CHUNK_BAR();

#pragma unroll
    for (int c = 0; c < NC; ++c) {
        COMPUTE(c, c & 1);
        if (c + 1 < NC) {
            WRITEC((c + 1) & 1);          // waits (counted) on its own loads only
            if (c + 2 < NC) LOADC(c + 2); // in flight across next COMPUTE
            CHUNK_BAR();
        }
    }
#undef CHUNK_BAR

    const float rs = rsqrtf(1.f + 1e-5f);
    if (OUT_F32) {
        float* out = (float*)outv;
#pragma unroll
        for (int mt = 0; mt < 4; ++mt) {
#pragma unroll
            for (int reg = 0; reg < 4; ++reg) {
                int co = wm * 64 + mt * 16 + q * 4 + reg;
                float sc = g[co] * rs, bb = be[co];
#pragma unroll
                for (int nt = 0; nt < 3; ++nt) {
                    int l = l0 + wn * 48 + nt * 16 + lx;
                    out[((size_t)b * 128 + co) * LPIX + l] =
                        fmaxf(fmaf(acc[mt][nt][reg], sc, bb), 0.f);
                }
            }
        }
    } else {
        u16* out = (u16*)outv;
        for (int mh = 0; mh < 2; ++mh) {
            __syncthreads();              // all COMPUTE reads done / prev pack done
            if (wm == mh) {
#pragma unroll
                for (int mt = 0; mt < 4; ++mt)
#pragma unroll
                    for (int nt = 0; nt < 3; ++nt)
#pragma unroll
                        for (int reg = 0; reg < 4; ++reg)
                            sT[(wn * 48 + nt * 16 + lx) * 65 + mt * 16 + q * 4 + reg] =
                                acc[mt][nt][reg];
            }
            __syncthreads();
            for (int i = tid; i < 768; i += 256) {
                int cog = i & 7, px = i >> 3;
                union { short8 v8; u16 u[8]; } pk;
#pragma unroll
                for (int j = 0; j < 8; ++j) {
                    int co = mh * 64 + cog * 8 + j;
                    pk.u[j] = f2bf(fmaxf(fmaf(sT[px * 65 + cog * 8 + j], g[co] * rs, be[co]), 0.f));
                }
                *(short8*)&out[((size_t)b * LPIX + l0 + px) * 128 + mh * 64 + cog * 8] = pk.v8;
            }
        }
    }
}

// ---------------------------------------------------------------------------
// 128->128 linear + bias via MFMA. in/out NHWC-flat bf16 [b*L][128].
// grid 1152 (64 px per block), block 256 (2x2 waves: M=64 x N=32).
// ---------------------------------------------------------------------------
__global__ __launch_bounds__(256) void linear_mfma(
    const u16* __restrict__ in, const u16* __restrict__ wp,
    const float* __restrict__ bias, u16* __restrict__ out)
{
    const int l0 = blockIdx.x * 64;
    const int tid = threadIdx.x, lane = tid & 63, wv = tid >> 6;
    const int wm = wv >> 1, wn = wv & 1;
    const int lx = lane & 15, q = lane >> 4;

    __shared__ char smem[4 * 64 * 40 * 2 + 4 * 128 * 40 * 2];   // 61,440 B
    u16* sX = (u16*)smem;                        // [c4][px 64][32 pitch 40]
    u16* sW = (u16*)(smem + 4 * 64 * 40 * 2);    // [c4][co 128][32 pitch 40]
    float* sT = (float*)smem;                    // epilogue [64][65]

    for (int i = tid; i < 1024; i += 256) {
        int k8 = i & 15, px = i >> 4;
        short8 v = *(const short8*)&in[((size_t)(l0 + px)) * 128 + k8 * 8];
        *(short8*)&sX[((k8 >> 2) * 64 + px) * 40 + (k8 & 3) * 8] = v;
    }
    for (int i = tid; i < 2048; i += 256) {
        int k8 = i & 15, co = i >> 4;
        short8 v = *(const short8*)&wp[(size_t)co * 128 + k8 * 8];
        *(short8*)&sW[((k8 >> 2) * 128 + co) * 40 + (k8 & 3) * 8] = v;
    }
    __syncthreads();

    f32x4 acc[4][2];
#pragma unroll
    for (int mt = 0; mt < 4; ++mt)
#pragma unroll
        for (int nt = 0; nt < 2; ++nt) acc[mt][nt] = (f32x4){0.f, 0.f, 0.f, 0.f};

#pragma unroll
    for (int c4 = 0; c4 < 4; ++c4) {
        short8 af[4], bfr[2];
#pragma unroll
        for (int mt = 0; mt < 4; ++mt)
            af[mt] = *(const short8*)&sW[(c4 * 128 + wm * 64 + mt * 16 + lx) * 40 + q * 8];
#pragma unroll
        for (int nt = 0; nt < 2; ++nt)
            bfr[nt] = *(const short8*)&sX[(c4 * 64 + wn * 32 + nt * 16 + lx) * 40 + q * 8];
#pragma unroll
        for (int mt = 0; mt < 4; ++mt)
#pragma unroll
            for (int nt = 0; nt < 2; ++nt)
                acc[mt][nt] = __builtin_amdgcn_mfma_f32_16x16x32_bf16(
                    af[mt], bfr[nt], acc[mt][nt], 0, 0, 0);
    }

    for (int mh = 0; mh < 2; ++mh) {
        __syncthreads();
        if (wm == mh) {
#pragma unroll
            for (int mt = 0; mt < 4; ++mt)
#pragma unroll
                for (int nt = 0; nt < 2; ++nt)
#pragma unroll
                    for (int reg = 0; reg < 4; ++reg)
                        sT[(wn * 32 + nt * 16 + lx) * 65 + mt * 16 + q * 4 + reg] =
                            acc[mt][nt][reg];
        }
        __syncthreads();
        for (int i = tid; i < 512; i += 256) {
            int cog = i & 7, px = i >> 3;
            union { short8 v8; u16 u[8]; } pk;
#pragma unroll
            for (int j = 0; j < 8; ++j) {
                int co = mh * 64 + cog * 8 + j;
                pk.u[j] = f2bf(sT[px * 65 + cog * 8 + j] + bias[co]);
            }
            *(short8*)&out[((size_t)(l0 + px)) * 128 + mh * 64 + cog * 8] = pk.v8;
        }
    }
}

// ---------------------------------------------------------------------------
// attn logits GEMM (MFMA) + bias + scale + softmax over q(9).
// grid (144 l-tiles of 64 px, 4 h, 8 b), block 256 (4 waves).
// ---------------------------------------------------------------------------
__global__ __launch_bounds__(256) void attn_mfma(
    const u16* __restrict__ fgb, const u16* __restrict__ awb,
    const float* __restrict__ ab, u16* __restrict__ A)
{
    const int lt = blockIdx.x, h = blockIdx.y, b = blockIdx.z;
    const int l0 = lt * 64;
    const int tid = threadIdx.x, lane = tid & 63, wv = tid >> 6;
    const int lx = lane & 15, q = lane >> 4;

    __shared__ char smem[4 * 64 * 40 * 2 + 4 * 96 * 40 * 2];   // 51,200 B
    u16* sX = (u16*)smem;                        // [c4][px 64][32 pitch 40]
    u16* sW = (u16*)(smem + 4 * 64 * 40 * 2);    // [c4][row 96][32 pitch 40]
    float* sL = (float*)smem;                    // epilogue logits [px 64][pitch 97]

    for (int i = tid; i < 1024; i += 256) {
        int k8 = i & 15, px = i >> 4;
        short8 v = *(const short8*)&fgb[((size_t)b * LPIX + l0 + px) * 128 + k8 * 8];
        *(short8*)&sX[((k8 >> 2) * 64 + px) * 40 + (k8 & 3) * 8] = v;
    }
    for (int i = tid; i < 1536; i += 256) {
        int k8 = i & 15, rr = i >> 4;           // rr 0..95, rows 81..95 zero-pad
        short8 v = {0, 0, 0, 0, 0, 0, 0, 0};
        if (rr < 81)
            v = *(const short8*)&awb[(size_t)(h * 81 + rr) * 128 + k8 * 8];
        *(short8*)&sW[((k8 >> 2) * 96 + rr) * 40 + (k8 & 3) * 8] = v;
    }
    __syncthreads();

    f32x4 acc[6];
#pragma unroll
    for (int j = 0; j < 6; ++j) acc[j] = (f32x4){0.f, 0.f, 0.f, 0.f};

#pragma unroll
    for (int c4 = 0; c4 < 4; ++c4) {
        short8 af = *(const short8*)&sX[(c4 * 64 + wv * 16 + lx) * 40 + q * 8];
#pragma unroll
        for (int j = 0; j < 6; ++j) {
            short8 bfr = *(const short8*)&sW[(c4 * 96 + j * 16 + lx) * 40 + q * 8];
            acc[j] = __builtin_amdgcn_mfma_f32_16x16x32_bf16(af, bfr, acc[j], 0, 0, 0);
        }
    }

    __syncthreads();   // done reading sX/sW; reuse as sL
#pragma unroll
    for (int j = 0; j < 6; ++j)
#pragma unroll
        for (int reg = 0; reg < 4; ++reg)
            sL[(wv * 16 + q * 4 + reg) * 97 + j * 16 + lx] = acc[j][reg];
    __syncthreads();

    for (int t = tid; t < 576; t += 256) {
        int px = t & 63, p = t >> 6;
        const int rbase = h * 81 + p * 9;
        float lg[9], m = -1e30f;
#pragma unroll
        for (int qq = 0; qq < 9; ++qq) {
            lg[qq] = (sL[px * 97 + p * 9 + qq] + ab[rbase + qq]) * kScale;
            m = fmaxf(m, lg[qq]);
        }
        float s = 0.f;
#pragma unroll
        for (int qq = 0; qq < 9; ++qq) { lg[qq] = __expf(lg[qq] - m); s += lg[qq]; }
        float inv = 1.f / s;
        u16* Ab = &A[(((size_t)(b * 4 + h) * 9 + p) * 9) * LPIX + l0 + px];
#pragma unroll
        for (int qq = 0; qq < 9; ++qq) Ab[(size_t)qq * LPIX] = f2bf(lg[qq] * inv);
    }
}

// ---------------------------------------------------------------------------
// fused einsum + fold (5x5 stencil collapse).
// Block 384 = one head x 4 full rows (384 px). Coalesced A reads (lane=px),
// v staged per-head in LDS (rows y0-2..y0+5 x 96 x 32ch bf16 = 49,152 B).
// grid (24 y-tiles, 4 h, 8 b).
// ---------------------------------------------------------------------------
__global__ __launch_bounds__(384, 4) void attn_fold(
    const u16* __restrict__ A, const u16* __restrict__ v,
    u16* __restrict__ out)
{
    const int yt = blockIdx.x, h = blockIdx.y, b = blockIdx.z;
    const int y0 = yt * 4;
    const int tid = threadIdx.x;          // 0..383
    const int yl  = tid / 96;             // 0..3
    const int x   = tid - yl * 96;
    const int y   = y0 + yl;
    const int l   = y * 96 + x;

    __shared__ u16 sV[8 * 96 * 32];       // [r 8][xx 96][c 32] bf16 = 49,152 B

    // ---- stage v rows y0-2 .. y0+5 (this head's 32 ch) ----
    const u16* vb = v + (size_t)b * LPIX * 128 + h * 32;
    for (int t = tid; t < 3072; t += 384) {
        int k = t & 3, s = t >> 2;        // s = r*96+xx, k = uint4 within 64B
        int r = s / 96, xx = s - r * 96;
        int gy = y0 - 2 + r;
        uint4 uu = make_uint4(0u, 0u, 0u, 0u);
        if ((unsigned)gy < 96u)
            uu = *(const uint4*)&vb[(size_t)(gy * 96 + xx) * 128 + k * 8];
        *(uint4*)&sV[(size_t)s * 32 + k * 8] = uu;
    }

    // ---- stencil S[5][5] from 9 taps x 9 q of A (coalesced bf16 reads) ----
    float S[25];
#pragma unroll
    for (int i = 0; i < 25; ++i) S[i] = 0.f;

    const u16* Ab = A + ((size_t)(b * 4 + h) * 81) * (size_t)LPIX;
#pragma unroll
    for (int ki = 0; ki < 3; ++ki) {
        const int ly = y + 1 - ki;
        const bool vy = ((unsigned)ly < 96u);
#pragma unroll
        for (int kj = 0; kj < 3; ++kj) {
            const int lx2 = x + 1 - kj;
            if (vy && (unsigned)lx2 < 96u) {
                const u16* Ap = Ab + (size_t)(ki * 3 + kj) * 9 * (size_t)LPIX
                              + (ly * 96 + lx2);
#pragma unroll
                for (int qq = 0; qq < 9; ++qq) {
                    const int qi = qq / 3, qj = qq - qi * 3;
                    S[(qi - ki + 2) * 5 + (qj - kj + 2)] += bf2f(Ap[(size_t)qq * LPIX]);
                }
            }
        }
    }

    __syncthreads();   // staging complete before LDS reads

    // ---- 5x5 stencil over LDS v tile ----
    float acc[32];
#pragma unroll
    for (int c = 0; c < 32; ++c) acc[c] = 0.f;

#pragma unroll
    for (int oy = 0; oy < 5; ++oy) {
        const int r = yl + oy;            // LDS row: gy = y0-2+r = y+oy-2
#pragma unroll
        for (int ox = 0; ox < 5; ++ox) {
            const int xx = x + ox - 2;
            if ((unsigned)xx >= 96u) continue;
            const float sc = S[oy * 5 + ox];
            const u16* vp = &sV[(size_t)(r * 96 + xx) * 32];
#pragma unroll
            for (int c8 = 0; c8 < 4; ++c8) {
                const uint4 uu = *(const uint4*)&vp[c8 * 8];
                acc[c8 * 8 + 0] = fmaf(sc, __uint_as_float(uu.x << 16),          acc[c8 * 8 + 0]);
                acc[c8 * 8 + 1] = fmaf(sc, __uint_as_float(uu.x & 0xffff0000u), acc[c8 * 8 + 1]);
                acc[c8 * 8 + 2] = fmaf(sc, __uint_as_float(uu.y << 16),          acc[c8 * 8 + 2]);
                acc[c8 * 8 + 3] = fmaf(sc, __uint_as_float(uu.y & 0xffff0000u), acc[c8 * 8 + 3]);
                acc[c8 * 8 + 4] = fmaf(sc, __uint_as_float(uu.z << 16),          acc[c8 * 8 + 4]);
                acc[c8 * 8 + 5] = fmaf(sc, __uint_as_float(uu.z & 0xffff0000u), acc[c8 * 8 + 5]);
                acc[c8 * 8 + 6] = fmaf(sc, __uint_as_float(uu.w << 16),          acc[c8 * 8 + 6]);
                acc[c8 * 8 + 7] = fmaf(sc, __uint_as_float(uu.w & 0xffff0000u), acc[c8 * 8 + 7]);
            }
        }
    }

    u16* ob = &out[((size_t)b * LPIX + l) * 128 + h * 32];
#pragma unroll
    for (int gidx = 0; gidx < 4; ++gidx) {
        union { short8 v8; u16 u[8]; } pk;
#pragma unroll
        for (int j = 0; j < 8; ++j) pk.u[j] = f2bf(acc[gidx * 8 + j]);
        *(short8*)&ob[gidx * 8] = pk.v8;
    }
}

// ---------------------------------------------------------------------------
extern "C" void kernel_launch(void* const* d_in, const int* in_sizes, int n_in,
                              void* d_out, int out_size, void* d_ws, size_t ws_size,
                              hipStream_t stream)
{
    const float* x    = (const float*)d_in[0];
    const float* fg   = (const float*)d_in[1];
    const float* c1w  = (const float*)d_in[2];
    const float* bn1g = (const float*)d_in[3];
    const float* bn1b = (const float*)d_in[4];
    const float* c2w  = (const float*)d_in[5];
    const float* bn2g = (const float*)d_in[6];
    const float* bn2b = (const float*)d_in[7];
    const float* vw   = (const float*)d_in[8];
    const float* vb   = (const float*)d_in[9];
    const float* aw   = (const float*)d_in[10];
    const float* abv  = (const float*)d_in[11];
    const float* pw   = (const float*)d_in[12];
    const float* pb   = (const float*)d_in[13];
    const float* c3w  = (const float*)d_in[14];
    const float* bn3g = (const float*)d_in[15];
    const float* bn3b = (const float*)d_in[16];
    const float* c4w  = (const float*)d_in[17];
    const float* bn4g = (const float*)d_in[18];
    const float* bn4b = (const float*)d_in[19];

    char* wsp = (char*)d_ws;
    size_t off = 0;
    auto carve = [&](size_t bytes) {
        void* pp = wsp + off;
        off += (bytes + 255) & ~(size_t)255;
        return pp;
    };
    u16*   xb   = (u16*)carve((size_t)8 * LPIX * 64 * 2);     // x NHWC bf16
    u16*   fgb  = (u16*)carve((size_t)8 * LPIX * 128 * 2);    // fg NHWC bf16
    u16*   actA = (u16*)carve((size_t)8 * LPIX * 128 * 2);
    u16*   actB = (u16*)carve((size_t)8 * LPIX * 128 * 2);
    u16*   Abuf = (u16*)carve((size_t)8 * 324 * LPIX * 2);    // A bf16
    u16*   w1p  = (u16*)carve((size_t)9 * 2 * 128 * 32 * 2);
    u16*   w2p  = (u16*)carve((size_t)9 * 4 * 128 * 32 * 2);
    u16*   w3p  = (u16*)carve((size_t)9 * 4 * 128 * 32 * 2);
    u16*   w4p  = (u16*)carve((size_t)9 * 4 * 128 * 32 * 2);
    u16*   vwp  = (u16*)carve((size_t)128 * 128 * 2);
    u16*   pwp  = (u16*)carve((size_t)128 * 128 * 2);
    u16*   awb  = (u16*)carve((size_t)324 * 128 * 2);

    // --- pre-casts ---
    cast_nchw_nhwc<64><<<dim3(HW, 8), 256, 0, stream>>>(x, xb);
    cast_nchw_nhwc<128><<<dim3(HW, 8), 256, 0, stream>>>(fg, fgb);
    cast_conv_w<<<(9 * 64 * 128 + 255) / 256, 256, 0, stream>>>(c1w, w1p, 64);
    cast_conv_w<<<(9 * 128 * 128 + 255) / 256, 256, 0, stream>>>(c2w, w2p, 128);
    cast_conv_w<<<(9 * 128 * 128 + 255) / 256, 256, 0, stream>>>(c3w, w3p, 128);
    cast_conv_w<<<(9 * 128 * 128 + 255) / 256, 256, 0, stream>>>(c4w, w4p, 128);
    cast_mat<<<(16384 + 255) / 256, 256, 0, stream>>>(vw, vwp, 16384);
    cast_mat<<<(16384 + 255) / 256, 256, 0, stream>>>(pw, pwp, 16384);
    cast_mat<<<(324 * 128 + 255) / 256, 256, 0, stream>>>(aw, awb, 324 * 128);

    // --- pipeline ---
    conv_gemm<64, false><<<dim3(96, 8), 256, 0, stream>>>(xb, w1p, bn1g, bn1b, actA);
    conv_gemm<128, false><<<dim3(96, 8), 256, 0, stream>>>(actA, w2p, bn2g, bn2b, actB);
    linear_mfma<<<1152, 256, 0, stream>>>(actB, vwp, vb, actA);                 // v
    attn_mfma<<<dim3(144, 4, 8), 256, 0, stream>>>(fgb, awb, abv, Abuf);
    attn_fold<<<dim3(24, 4, 8), 384, 0, stream>>>(Abuf, actA, actB);            // folded
    linear_mfma<<<1152, 256, 0, stream>>>(actB, pwp, pb, actA);                 // p
    conv_gemm<128, false><<<dim3(96, 8), 256, 0, stream>>>(actA, w3p, bn3g, bn3b, actB);
    conv_gemm<128, true><<<dim3(96, 8), 256, 0, stream>>>(actB, w4p, bn4g, bn4b, d_out);
}

// Round 2
// 368.222 us; speedup vs baseline: 1.1367x; 1.1367x over previous
//
#include <hip/hip_runtime.h>
#include <math.h>

typedef __attribute__((ext_vector_type(8))) short short8;
typedef __attribute__((ext_vector_type(4))) float f32x4;
typedef unsigned short u16;
typedef unsigned int u32;

#define HW   96
#define LPIX 9216
static constexpr float kScale = 0.17677669529663687f;  // 1/sqrt(32)

__device__ inline u16 f2bf(float f) {
    u32 x = __float_as_uint(f);
    return (u16)((x + 0x7fffu + ((x >> 16) & 1u)) >> 16);   // RNE
}
__device__ inline float bf2f(u16 v) { return __uint_as_float((u32)v << 16); }

// global -> LDS direct copy, 16B per lane. LDS dest is wave-uniform base +
// lane*16 (HW semantics); global src is per-lane.
typedef __attribute__((address_space(1))) const void gas_t;
typedef __attribute__((address_space(3))) void las_t;
__device__ __forceinline__ void g2lds16(const void* g, void* l) {
    __builtin_amdgcn_global_load_lds((gas_t*)g, (las_t*)l, 16, 0, 0);
}

// ---------------------------------------------------------------------------
// NCHW fp32 -> NHWC bf16 transpose-cast. grid (96 y, 8 b), block 256.
// ---------------------------------------------------------------------------
template <int C>
__global__ __launch_bounds__(256) void cast_nchw_nhwc(
    const float* __restrict__ in, u16* __restrict__ out)
{
    const int y = blockIdx.x, b = blockIdx.y, tid = threadIdx.x;
    __shared__ float sT[HW * C];
    for (int i = tid; i < HW * C; i += 256) {
        int c = i / HW, xx = i - c * HW;
        sT[xx * C + c] = in[(((size_t)b * C + c) * HW + y) * HW + xx];
    }
    __syncthreads();
    for (int i = tid; i < HW * (C / 8); i += 256) {
        int c8 = i % (C / 8), xx = i / (C / 8);
        union { short8 v8; u16 u[8]; } pk;
#pragma unroll
        for (int j = 0; j < 8; ++j) pk.u[j] = f2bf(sT[xx * C + c8 * 8 + j]);
        *(short8*)&out[(((size_t)b * HW + y) * HW + xx) * C + c8 * 8] = pk.v8;
    }
}

// ---------------------------------------------------------------------------
// conv weights [co 128][ci CIN][3][3] fp32 -> swizzled granule layout for
// direct global_load_lds staging:
//   per (coh 2, c NC) group: 2304 granules of 16B; granule
//   gi = f*256 + m*4 + s holds logical (f, co=coh*64+m, q=(s-(m>>1))&3),
//   i.e. ci = c*32 + q*8 + e  (e = u16 within granule).
// The (m>>1) slot rotation makes the LDS ds_read_b128 pattern 2-way
// conflict-free despite the forced 64B linear pitch.
// ---------------------------------------------------------------------------
__global__ void cast_conv_w(const float* __restrict__ w, u16* __restrict__ wp, int CIN)
{
    int n = 9 * CIN * 128;
    int i = blockIdx.x * 256 + threadIdx.x;
    if (i >= n) return;
    int NC = CIN >> 5;
    int e  = i & 7;
    int gr = i >> 3;                 // granule index
    int cc = gr / 2304;              // (coh*NC + c)
    int gi = gr - cc * 2304;
    int coh = cc / NC, c = cc - coh * NC;
    int f = gi >> 8;
    int m = (gi >> 2) & 63;
    int s = gi & 3;
    int qq = (s - (m >> 1)) & 3;
    int co = coh * 64 + m;
    int ci = c * 32 + qq * 8 + e;
    wp[i] = f2bf(w[(size_t)(co * CIN + ci) * 9 + f]);
}

// dense matrix fp32 -> bf16 (same layout)
__global__ void cast_mat(const float* __restrict__ in, u16* __restrict__ out, int n)
{
    int i = blockIdx.x * 256 + threadIdx.x;
    if (i < n) out[i] = f2bf(in[i]);
}

// ---------------------------------------------------------------------------
// conv3x3 + BN + ReLU, v3: weights-in-LDS, global_load_lds everything.
//  * block = 64 co (coh half) x 3 rows x 96 px; 192 threads = 3 waves,
//    each wave M=64(co) x N=96(one row), acc[4][6].
//  * grid (64, 8) = 512 blocks = exactly 2/CU (LDS 67.7KB -> 2 resident).
//  * per 32-ci chunk: stage weights (36.9KB, 2304 granules) + flat-pixel
//    halo (482 rows x 4 granules = 30.8KB) via global_load_lds(16B);
//    single bulk vmcnt(0) + barrier, then 9 taps x 24 MFMA from LDS with
//    ZERO global loads in the compute phase.
//  * granule-slot swizzle (slot = (q + (row>>1))&3) on both stage-src and
//    read side -> 2-way bank conflicts (free) on af/bfr ds_read_b128.
//  * halo OOB rows: address-clamped (garbage), masked by ok-predicate.
//  * XCD pairing: coh pair (x, x+32) and row-adjacent groups (x, x+8)
//    land on the same XCD for halo/weight L2 reuse.
// ---------------------------------------------------------------------------
template <int CIN, bool OUT_F32>
__global__ __launch_bounds__(192, 2) void conv_gemm(
    const u16* __restrict__ in, const u16* __restrict__ wp,
    const float* __restrict__ g, const float* __restrict__ be, void* outv)
{
    constexpr int NC    = CIN / 32;      // 32-ci chunks (2 or 4)
    constexpr int WBYT  = 36864;         // weight region bytes (2304 granules)
    constexpr int NHG   = 1928;          // halo granules (482 rows x 4)

    const int bx  = blockIdx.x;          // 0..63
    const int b   = blockIdx.y;
    const int coh = bx >> 5;
    const int gg  = bx & 31;
    const int gsw = (gg & 7) * 4 + (gg >> 3);   // row-group swizzle (same-XCD neighbors)
    const int y0  = gsw * 3;             // rows y0..y0+2
    const int l0h = y0 * 96 - 97;        // halo flat-pixel origin

    const int tid = threadIdx.x, lane = tid & 63, wv = tid >> 6;  // wv = row
    const int lx = lane & 15, q = lane >> 4;

    __shared__ __align__(16) char smem[WBYT + NHG * 16];   // 67,712 B
    float* sT = (float*)smem;            // epilogue [144 px][65] f32 (37,440 B)

    // precomputed per-lane pieces
    const int aoff = lx * 64 + (((q + (lx >> 1)) & 3) << 4);   // af addr (weights)
    const int pb   = wv * 96 + lx;                             // bfr pixel-row base

    f32x4 acc[4][6];
#pragma unroll
    for (int mt = 0; mt < 4; ++mt)
#pragma unroll
        for (int nt = 0; nt < 6; ++nt) acc[mt][nt] = (f32x4){0.f, 0.f, 0.f, 0.f};

    const u16* inb = in + (size_t)b * LPIX * CIN;

#pragma unroll
    for (int c = 0; c < NC; ++c) {
        if (c) __syncthreads();          // previous chunk's readers done

        // ---- stage weights: 2304 granules, linear LDS, pre-swizzled source ----
        {
            const u16* wqb = wp + ((size_t)(coh * NC + c)) * 2304 * 8;
#pragma unroll
            for (int j = 0; j < 12; ++j) {
                int gj = j * 192 + tid;
                g2lds16(&wqb[(size_t)gj * 8],
                        (char*)smem + (j * 192 + wv * 64) * 16);
            }
        }
        // ---- stage halo: 1928 granules, clamped rows, swizzled source q ----
#pragma unroll
        for (int i = 0; i < 11; ++i) {
            int gi = i * 192 + tid;
            if (gi < NHG) {
                int p = gi >> 2, s = gi & 3;
                int qq = (s - (p >> 1)) & 3;
                int lh = l0h + p;
                lh = lh < 0 ? 0 : (lh >= LPIX ? LPIX - 1 : lh);
                g2lds16(&inb[(size_t)lh * CIN + c * 32 + qq * 8],
                        (char*)smem + WBYT + (i * 192 + wv * 64) * 16);
            }
        }
        asm volatile("s_waitcnt vmcnt(0)" ::: "memory");
        __builtin_amdgcn_s_barrier();
        asm volatile("" ::: "memory");

        // ---- compute: 9 taps x 24 MFMA, all operands from LDS ----
#pragma unroll
        for (int f = 0; f < 9; ++f) {
            const int dy = f / 3 - 1, dx = f % 3 - 1;
            const int off = dy * 96 + dx + 97;           // [0,194]
            const bool vy = (unsigned)(y0 + wv + dy) < 96u;
            short8 af[4], bfr[6];
#pragma unroll
            for (int mt = 0; mt < 4; ++mt)
                af[mt] = *(const short8*)((const char*)smem + f * 4096 + mt * 1024 + aoff);
#pragma unroll
            for (int nt = 0; nt < 6; ++nt) {
                int p = pb + nt * 16 + off;
                int slot = (q + (p >> 1)) & 3;
                short8 t8 = *(const short8*)((const char*)smem + WBYT + p * 64 + slot * 16);
                bool ok = vy & ((unsigned)(nt * 16 + lx + dx) < 96u);
                bfr[nt] = ok ? t8 : (short8){0, 0, 0, 0, 0, 0, 0, 0};
            }
#pragma unroll
            for (int mt = 0; mt < 4; ++mt)
#pragma unroll
                for (int nt = 0; nt < 6; ++nt)
                    acc[mt][nt] = __builtin_amdgcn_mfma_f32_16x16x32_bf16(
                        af[mt], bfr[nt], acc[mt][nt], 0, 0, 0);
        }
    }

    const float rs = rsqrtf(1.f + 1e-5f);
    if (OUT_F32) {
        float* out = (float*)outv;
#pragma unroll
        for (int mt = 0; mt < 4; ++mt) {
#pragma unroll
            for (int reg = 0; reg < 4; ++reg) {
                int co = coh * 64 + mt * 16 + q * 4 + reg;
                float sc = g[co] * rs, bb = be[co];
#pragma unroll
                for (int nt = 0; nt < 6; ++nt) {
                    int l = (y0 + wv) * 96 + nt * 16 + lx;
                    out[((size_t)b * 128 + co) * LPIX + l] =
                        fmaxf(fmaf(acc[mt][nt][reg], sc, bb), 0.f);
                }
            }
        }
    } else {
        u16* out = (u16*)outv;
#pragma unroll
        for (int hh = 0; hh < 2; ++hh) {               // two 48-px halves
            __syncthreads();
#pragma unroll
            for (int mt = 0; mt < 4; ++mt)
#pragma unroll
                for (int nn = 0; nn < 3; ++nn) {
                    int nt = hh * 3 + nn;
#pragma unroll
                    for (int reg = 0; reg < 4; ++reg)
                        sT[(wv * 48 + nn * 16 + lx) * 65 + mt * 16 + q * 4 + reg] =
                            acc[mt][nt][reg];
                }
            __syncthreads();
            for (int i = tid; i < 1152; i += 192) {
                int cog = i & 7, pxl = i >> 3;
                int wrr = pxl / 48, ofs = pxl - wrr * 48;
                int l = (y0 + wrr) * 96 + hh * 48 + ofs;
                union { short8 v8; u16 u[8]; } pk;
#pragma unroll
                for (int j = 0; j < 8; ++j) {
                    int co = coh * 64 + cog * 8 + j;
                    pk.u[j] = f2bf(fmaxf(fmaf(sT[pxl * 65 + cog * 8 + j], g[co] * rs, be[co]), 0.f));
                }
                *(short8*)&out[((size_t)b * LPIX + l) * 128 + coh * 64 + cog * 8] = pk.v8;
            }
        }
    }
}

// ---------------------------------------------------------------------------
// 128->128 linear + bias via MFMA. in/out NHWC-flat bf16 [b*L][128].
// grid 1152 (64 px per block), block 256 (2x2 waves: M=64 x N=32).
// ---------------------------------------------------------------------------
__global__ __launch_bounds__(256) void linear_mfma(
    const u16* __restrict__ in, const u16* __restrict__ wp,
    const float* __restrict__ bias, u16* __restrict__ out)
{
    const int l0 = blockIdx.x * 64;
    const int tid = threadIdx.x, lane = tid & 63, wv = tid >> 6;
    const int wm = wv >> 1, wn = wv & 1;
    const int lx = lane & 15, q = lane >> 4;

    __shared__ char smem[4 * 64 * 40 * 2 + 4 * 128 * 40 * 2];   // 61,440 B
    u16* sX = (u16*)smem;                        // [c4][px 64][32 pitch 40]
    u16* sW = (u16*)(smem + 4 * 64 * 40 * 2);    // [c4][co 128][32 pitch 40]
    float* sT = (float*)smem;                    // epilogue [64][65]

    for (int i = tid; i < 1024; i += 256) {
        int k8 = i & 15, px = i >> 4;
        short8 v = *(const short8*)&in[((size_t)(l0 + px)) * 128 + k8 * 8];
        *(short8*)&sX[((k8 >> 2) * 64 + px) * 40 + (k8 & 3) * 8] = v;
    }
    for (int i = tid; i < 2048; i += 256) {
        int k8 = i & 15, co = i >> 4;
        short8 v = *(const short8*)&wp[(size_t)co * 128 + k8 * 8];
        *(short8*)&sW[((k8 >> 2) * 128 + co) * 40 + (k8 & 3) * 8] = v;
    }
    __syncthreads();

    f32x4 acc[4][2];
#pragma unroll
    for (int mt = 0; mt < 4; ++mt)
#pragma unroll
        for (int nt = 0; nt < 2; ++nt) acc[mt][nt] = (f32x4){0.f, 0.f, 0.f, 0.f};

#pragma unroll
    for (int c4 = 0; c4 < 4; ++c4) {
        short8 af[4], bfr[2];
#pragma unroll
        for (int mt = 0; mt < 4; ++mt)
            af[mt] = *(const short8*)&sW[(c4 * 128 + wm * 64 + mt * 16 + lx) * 40 + q * 8];
#pragma unroll
        for (int nt = 0; nt < 2; ++nt)
            bfr[nt] = *(const short8*)&sX[(c4 * 64 + wn * 32 + nt * 16 + lx) * 40 + q * 8];
#pragma unroll
        for (int mt = 0; mt < 4; ++mt)
#pragma unroll
            for (int nt = 0; nt < 2; ++nt)
                acc[mt][nt] = __builtin_amdgcn_mfma_f32_16x16x32_bf16(
                    af[mt], bfr[nt], acc[mt][nt], 0, 0, 0);
    }

    for (int mh = 0; mh < 2; ++mh) {
        __syncthreads();
        if (wm == mh) {
#pragma unroll
            for (int mt = 0; mt < 4; ++mt)
#pragma unroll
                for (int nt = 0; nt < 2; ++nt)
#pragma unroll
                    for (int reg = 0; reg < 4; ++reg)
                        sT[(wn * 32 + nt * 16 + lx) * 65 + mt * 16 + q * 4 + reg] =
                            acc[mt][nt][reg];
        }
        __syncthreads();
        for (int i = tid; i < 512; i += 256) {
            int cog = i & 7, px = i >> 3;
            union { short8 v8; u16 u[8]; } pk;
#pragma unroll
            for (int j = 0; j < 8; ++j) {
                int co = mh * 64 + cog * 8 + j;
                pk.u[j] = f2bf(sT[px * 65 + cog * 8 + j] + bias[co]);
            }
            *(short8*)&out[((size_t)(l0 + px)) * 128 + mh * 64 + cog * 8] = pk.v8;
        }
    }
}

// ---------------------------------------------------------------------------
// attn logits GEMM (MFMA) + bias + scale + softmax over q(9).
// grid (144 l-tiles of 64 px, 4 h, 8 b), block 256 (4 waves).
// ---------------------------------------------------------------------------
__global__ __launch_bounds__(256) void attn_mfma(
    const u16* __restrict__ fgb, const u16* __restrict__ awb,
    const float* __restrict__ ab, u16* __restrict__ A)
{
    const int lt = blockIdx.x, h = blockIdx.y, b = blockIdx.z;
    const int l0 = lt * 64;
    const int tid = threadIdx.x, lane = tid & 63, wv = tid >> 6;
    const int lx = lane & 15, q = lane >> 4;

    __shared__ char smem[4 * 64 * 40 * 2 + 4 * 96 * 40 * 2];   // 51,200 B
    u16* sX = (u16*)smem;                        // [c4][px 64][32 pitch 40]
    u16* sW = (u16*)(smem + 4 * 64 * 40 * 2);    // [c4][row 96][32 pitch 40]
    float* sL = (float*)smem;                    // epilogue logits [px 64][pitch 97]

    for (int i = tid; i < 1024; i += 256) {
        int k8 = i & 15, px = i >> 4;
        short8 v = *(const short8*)&fgb[((size_t)b * LPIX + l0 + px) * 128 + k8 * 8];
        *(short8*)&sX[((k8 >> 2) * 64 + px) * 40 + (k8 & 3) * 8] = v;
    }
    for (int i = tid; i < 1536; i += 256) {
        int k8 = i & 15, rr = i >> 4;           // rr 0..95, rows 81..95 zero-pad
        short8 v = {0, 0, 0, 0, 0, 0, 0, 0};
        if (rr < 81)
            v = *(const short8*)&awb[(size_t)(h * 81 + rr) * 128 + k8 * 8];
        *(short8*)&sW[((k8 >> 2) * 96 + rr) * 40 + (k8 & 3) * 8] = v;
    }
    __syncthreads();

    f32x4 acc[6];
#pragma unroll
    for (int j = 0; j < 6; ++j) acc[j] = (f32x4){0.f, 0.f, 0.f, 0.f};

#pragma unroll
    for (int c4 = 0; c4 < 4; ++c4) {
        short8 af = *(const short8*)&sX[(c4 * 64 + wv * 16 + lx) * 40 + q * 8];
#pragma unroll
        for (int j = 0; j < 6; ++j) {
            short8 bfr = *(const short8*)&sW[(c4 * 96 + j * 16 + lx) * 40 + q * 8];
            acc[j] = __builtin_amdgcn_mfma_f32_16x16x32_bf16(af, bfr, acc[j], 0, 0, 0);
        }
    }

    __syncthreads();   // done reading sX/sW; reuse as sL
#pragma unroll
    for (int j = 0; j < 6; ++j)
#pragma unroll
        for (int reg = 0; reg < 4; ++reg)
            sL[(wv * 16 + q * 4 + reg) * 97 + j * 16 + lx] = acc[j][reg];
    __syncthreads();

    for (int t = tid; t < 576; t += 256) {
        int px = t & 63, p = t >> 6;
        const int rbase = h * 81 + p * 9;
        float lg[9], m = -1e30f;
#pragma unroll
        for (int qq = 0; qq < 9; ++qq) {
            lg[qq] = (sL[px * 97 + p * 9 + qq] + ab[rbase + qq]) * kScale;
            m = fmaxf(m, lg[qq]);
        }
        float s = 0.f;
#pragma unroll
        for (int qq = 0; qq < 9; ++qq) { lg[qq] = __expf(lg[qq] - m); s += lg[qq]; }
        float inv = 1.f / s;
        u16* Ab = &A[(((size_t)(b * 4 + h) * 9 + p) * 9) * LPIX + l0 + px];
#pragma unroll
        for (int qq = 0; qq < 9; ++qq) Ab[(size_t)qq * LPIX] = f2bf(lg[qq] * inv);
    }
}

// ---------------------------------------------------------------------------
// fused einsum + fold (5x5 stencil collapse).
// Block 384 = one head x 4 full rows (384 px). Coalesced A reads (lane=px),
// v staged per-head in LDS (rows y0-2..y0+5 x 96 x 32ch bf16 = 49,152 B).
// grid (24 y-tiles, 4 h, 8 b).
// ---------------------------------------------------------------------------
__global__ __launch_bounds__(384, 4) void attn_fold(
    const u16* __restrict__ A, const u16* __restrict__ v,
    u16* __restrict__ out)
{
    const int yt = blockIdx.x, h = blockIdx.y, b = blockIdx.z;
    const int y0 = yt * 4;
    const int tid = threadIdx.x;          // 0..383
    const int yl  = tid / 96;             // 0..3
    const int x   = tid - yl * 96;
    const int y   = y0 + yl;
    const int l   = y * 96 + x;

    __shared__ u16 sV[8 * 96 * 32];       // [r 8][xx 96][c 32] bf16 = 49,152 B

    // ---- stage v rows y0-2 .. y0+5 (this head's 32 ch) ----
    const u16* vb = v + (size_t)b * LPIX * 128 + h * 32;
    for (int t = tid; t < 3072; t += 384) {
        int k = t & 3, s = t >> 2;        // s = r*96+xx, k = uint4 within 64B
        int r = s / 96, xx = s - r * 96;
        int gy = y0 - 2 + r;
        uint4 uu = make_uint4(0u, 0u, 0u, 0u);
        if ((unsigned)gy < 96u)
            uu = *(const uint4*)&vb[(size_t)(gy * 96 + xx) * 128 + k * 8];
        *(uint4*)&sV[(size_t)s * 32 + k * 8] = uu;
    }

    // ---- stencil S[5][5] from 9 taps x 9 q of A (coalesced bf16 reads) ----
    float S[25];
#pragma unroll
    for (int i = 0; i < 25; ++i) S[i] = 0.f;

    const u16* Ab = A + ((size_t)(b * 4 + h) * 81) * (size_t)LPIX;
#pragma unroll
    for (int ki = 0; ki < 3; ++ki) {
        const int ly = y + 1 - ki;
        const bool vy = ((unsigned)ly < 96u);
#pragma unroll
        for (int kj = 0; kj < 3; ++kj) {
            const int lx2 = x + 1 - kj;
            if (vy && (unsigned)lx2 < 96u) {
                const u16* Ap = Ab + (size_t)(ki * 3 + kj) * 9 * (size_t)LPIX
                              + (ly * 96 + lx2);
#pragma unroll
                for (int qq = 0; qq < 9; ++qq) {
                    const int qi = qq / 3, qj = qq - qi * 3;
                    S[(qi - ki + 2) * 5 + (qj - kj + 2)] += bf2f(Ap[(size_t)qq * LPIX]);
                }
            }
        }
    }

    __syncthreads();   // staging complete before LDS reads

    // ---- 5x5 stencil over LDS v tile ----
    float acc[32];
#pragma unroll
    for (int c = 0; c < 32; ++c) acc[c] = 0.f;

#pragma unroll
    for (int oy = 0; oy < 5; ++oy) {
        const int r = yl + oy;            // LDS row: gy = y0-2+r = y+oy-2
#pragma unroll
        for (int ox = 0; ox < 5; ++ox) {
            const int xx = x + ox - 2;
            if ((unsigned)xx >= 96u) continue;
            const float sc = S[oy * 5 + ox];
            const u16* vp = &sV[(size_t)(r * 96 + xx) * 32];
#pragma unroll
            for (int c8 = 0; c8 < 4; ++c8) {
                const uint4 uu = *(const uint4*)&vp[c8 * 8];
                acc[c8 * 8 + 0] = fmaf(sc, __uint_as_float(uu.x << 16),          acc[c8 * 8 + 0]);
                acc[c8 * 8 + 1] = fmaf(sc, __uint_as_float(uu.x & 0xffff0000u), acc[c8 * 8 + 1]);
                acc[c8 * 8 + 2] = fmaf(sc, __uint_as_float(uu.y << 16),          acc[c8 * 8 + 2]);
                acc[c8 * 8 + 3] = fmaf(sc, __uint_as_float(uu.y & 0xffff0000u), acc[c8 * 8 + 3]);
                acc[c8 * 8 + 4] = fmaf(sc, __uint_as_float(uu.z << 16),          acc[c8 * 8 + 4]);
                acc[c8 * 8 + 5] = fmaf(sc, __uint_as_float(uu.z & 0xffff0000u), acc[c8 * 8 + 5]);
                acc[c8 * 8 + 6] = fmaf(sc, __uint_as_float(uu.w << 16),          acc[c8 * 8 + 6]);
                acc[c8 * 8 + 7] = fmaf(sc, __uint_as_float(uu.w & 0xffff0000u), acc[c8 * 8 + 7]);
            }
        }
    }

    u16* ob = &out[((size_t)b * LPIX + l) * 128 + h * 32];
#pragma unroll
    for (int gidx = 0; gidx < 4; ++gidx) {
        union { short8 v8; u16 u[8]; } pk;
#pragma unroll
        for (int j = 0; j < 8; ++j) pk.u[j] = f2bf(acc[gidx * 8 + j]);
        *(short8*)&ob[gidx * 8] = pk.v8;
    }
}

// ---------------------------------------------------------------------------
extern "C" void kernel_launch(void* const* d_in, const int* in_sizes, int n_in,
                              void* d_out, int out_size, void* d_ws, size_t ws_size,
                              hipStream_t stream)
{
    const float* x    = (const float*)d_in[0];
    const float* fg   = (const float*)d_in[1];
    const float* c1w  = (const float*)d_in[2];
    const float* bn1g = (const float*)d_in[3];
    const float* bn1b = (const float*)d_in[4];
    const float* c2w  = (const float*)d_in[5];
    const float* bn2g = (const float*)d_in[6];
    const float* bn2b = (const float*)d_in[7];
    const float* vw   = (const float*)d_in[8];
    const float* vb   = (const float*)d_in[9];
    const float* aw   = (const float*)d_in[10];
    const float* abv  = (const float*)d_in[11];
    const float* pw   = (const float*)d_in[12];
    const float* pb   = (const float*)d_in[13];
    const float* c3w  = (const float*)d_in[14];
    const float* bn3g = (const float*)d_in[15];
    const float* bn3b = (const float*)d_in[16];
    const float* c4w  = (const float*)d_in[17];
    const float* bn4g = (const float*)d_in[18];
    const float* bn4b = (const float*)d_in[19];

    char* wsp = (char*)d_ws;
    size_t off = 0;
    auto carve = [&](size_t bytes) {
        void* pp = wsp + off;
        off += (bytes + 255) & ~(size_t)255;
        return pp;
    };
    u16*   xb   = (u16*)carve((size_t)8 * LPIX * 64 * 2);     // x NHWC bf16
    u16*   fgb  = (u16*)carve((size_t)8 * LPIX * 128 * 2);    // fg NHWC bf16
    u16*   actA = (u16*)carve((size_t)8 * LPIX * 128 * 2);
    u16*   actB = (u16*)carve((size_t)8 * LPIX * 128 * 2);
    u16*   Abuf = (u16*)carve((size_t)8 * 324 * LPIX * 2);    // A bf16
    u16*   w1p  = (u16*)carve((size_t)9 * 2 * 128 * 32 * 2);
    u16*   w2p  = (u16*)carve((size_t)9 * 4 * 128 * 32 * 2);
    u16*   w3p  = (u16*)carve((size_t)9 * 4 * 128 * 32 * 2);
    u16*   w4p  = (u16*)carve((size_t)9 * 4 * 128 * 32 * 2);
    u16*   vwp  = (u16*)carve((size_t)128 * 128 * 2);
    u16*   pwp  = (u16*)carve((size_t)128 * 128 * 2);
    u16*   awb  = (u16*)carve((size_t)324 * 128 * 2);

    // --- pre-casts ---
    cast_nchw_nhwc<64><<<dim3(HW, 8), 256, 0, stream>>>(x, xb);
    cast_nchw_nhwc<128><<<dim3(HW, 8), 256, 0, stream>>>(fg, fgb);
    cast_conv_w<<<(9 * 64 * 128 + 255) / 256, 256, 0, stream>>>(c1w, w1p, 64);
    cast_conv_w<<<(9 * 128 * 128 + 255) / 256, 256, 0, stream>>>(c2w, w2p, 128);
    cast_conv_w<<<(9 * 128 * 128 + 255) / 256, 256, 0, stream>>>(c3w, w3p, 128);
    cast_conv_w<<<(9 * 128 * 128 + 255) / 256, 256, 0, stream>>>(c4w, w4p, 128);
    cast_mat<<<(16384 + 255) / 256, 256, 0, stream>>>(vw, vwp, 16384);
    cast_mat<<<(16384 + 255) / 256, 256, 0, stream>>>(pw, pwp, 16384);
    cast_mat<<<(324 * 128 + 255) / 256, 256, 0, stream>>>(aw, awb, 324 * 128);

    // --- pipeline ---
    conv_gemm<64, false><<<dim3(64, 8), 192, 0, stream>>>(xb, w1p, bn1g, bn1b, actA);
    conv_gemm<128, false><<<dim3(64, 8), 192, 0, stream>>>(actA, w2p, bn2g, bn2b, actB);
    linear_mfma<<<1152, 256, 0, stream>>>(actB, vwp, vb, actA);                 // v
    attn_mfma<<<dim3(144, 4, 8), 256, 0, stream>>>(fgb, awb, abv, Abuf);
    attn_fold<<<dim3(24, 4, 8), 384, 0, stream>>>(Abuf, actA, actB);            // folded
    linear_mfma<<<1152, 256, 0, stream>>>(actB, pwp, pb, actA);                 // p
    conv_gemm<128, false><<<dim3(64, 8), 192, 0, stream>>>(actA, w3p, bn3g, bn3b, actB);
    conv_gemm<128, true><<<dim3(64, 8), 192, 0, stream>>>(actB, w4p, bn4g, bn4b, d_out);
}